// Round 4
// baseline (4696.695 us; speedup 1.0000x reference)
//
#include <hip/hip_runtime.h>
#include <cstdint>

#define NB 256

__device__ __forceinline__ float sigm(float x) { return 1.f / (1.f + __expf(-x)); }
__device__ __forceinline__ float tanh_(float x) { return 1.f - 2.f / (1.f + __expf(2.f * x)); }

__device__ __forceinline__ void fma4(float4& a, float s, const float4& x) {
    a.x = fmaf(s, x.x, a.x); a.y = fmaf(s, x.y, a.y);
    a.z = fmaf(s, x.z, a.z); a.w = fmaf(s, x.w, a.w);
}

// publish a float to the LLC (coherence point) via agent-scope store.
__device__ __forceinline__ void pub(float* p, float v) {
    __hip_atomic_store(p, v, __ATOMIC_RELAXED, __HIP_MEMORY_SCOPE_AGENT);
}

// ---------------- grid barrier (round-3 proven: no cache-invalidating fences) -
__device__ __forceinline__ void gbar(unsigned* flags, unsigned* bar1, unsigned g) {
    asm volatile("s_waitcnt vmcnt(0)" ::: "memory");  // this wave's pub stores at LLC
    __syncthreads();
    const int tid = threadIdx.x, bid = blockIdx.x;
    if (bid == 0) {
        if (tid > 0 && tid < NB) {
            while (__hip_atomic_load(&flags[tid], __ATOMIC_RELAXED,
                                     __HIP_MEMORY_SCOPE_AGENT) < g)
                __builtin_amdgcn_s_sleep(2);
        }
        __syncthreads();
        if (tid == 0)
            __hip_atomic_store(bar1, g, __ATOMIC_RELAXED, __HIP_MEMORY_SCOPE_AGENT);
    } else if (tid == 0) {
        __hip_atomic_store(&flags[bid], g, __ATOMIC_RELAXED, __HIP_MEMORY_SCOPE_AGENT);
        while (__hip_atomic_load(bar1, __ATOMIC_RELAXED,
                                 __HIP_MEMORY_SCOPE_AGENT) < g)
            __builtin_amdgcn_s_sleep(2);
    }
    __syncthreads();
}

// ---------------- init: states into transposed [h][b] slot-0 arenas ----------
__global__ __launch_bounds__(256) void k_init(const float* __restrict__ h0i,
                                              const float* __restrict__ c0i,
                                              const float* __restrict__ feedi,
                                              float* h0A, float* h1A, float* c0T, float* c1T,
                                              float* feedA, unsigned* barArr) {
    int t = blockIdx.x * 256 + threadIdx.x;  // 32768 = 512*64
    if (t < NB + 1) barArr[t] = 0u;          // flags[0..255] + bar1
    int hh = t >> 6, b = t & 63;
    h0A[t]   = h0i[b * 512 + hh];
    h1A[t]   = h0i[32768 + b * 512 + hh];
    c0T[t]   = c0i[b * 512 + hh];
    c1T[t]   = c0i[32768 + b * 512 + hh];
    feedA[t] = feedi[b * 512 + hh];
}

// ---------------- register-weight GEMM phase --------------------------------
// Thread (kq = tid>>4, grp = tid&15) owns 1 row x 4 k's per 128-k chunk, with
// weights pinned in wv[]. X staged chunk-wise into XT[k][b] with XOR swizzle
// col = b ^ (k&12) (float4-aligned; FMA reads become 2-way = free).
// Partial acc covers b = bcol..bcol+4*NJ-1; K-reduce done by caller.
template<int NCH, int GCH, int NJ>
__device__ __forceinline__ void gemm_phase(
    float* XT, const float4* wv, float4* acc,
    const float* s0T, const float* s1T, const float* s2T,
    const float* er, const int tid, const int kq, const int bcol)
{
    float4 st[4];
    const int q = tid & 7;
    // prefetch chunk 0
    if (GCH > 0) {
#pragma unroll
        for (int j = 0; j < 4; ++j)
            st[j] = *(const float4*)(er + (q + j * 8) * 4);
    } else {
#pragma unroll
        for (int j = 0; j < 4; ++j)
            st[j] = *(const float4*)(s0T + (size_t)(tid + j * 512) * 4);
    }
#pragma unroll
    for (int c = 0; c < NCH; ++c) {
        __syncthreads();   // previous XT/LDS consumers done
        if (GCH > 0 && c < GCH) {
            const int b = tid >> 3;
#pragma unroll
            for (int j = 0; j < 4; ++j) {
                int kl = (q + j * 8) * 4;
                int col = b ^ (kl & 12);   // (kl+i)&12 == kl&12 for i<4
                XT[(kl + 0) * 68 + col] = st[j].x;
                XT[(kl + 1) * 68 + col] = st[j].y;
                XT[(kl + 2) * 68 + col] = st[j].z;
                XT[(kl + 3) * 68 + col] = st[j].w;
            }
        } else {
#pragma unroll
            for (int j = 0; j < 4; ++j) {
                int f = tid + j * 512;
                int k = f >> 4, bq4 = (f & 15) * 4;
                *(float4*)&XT[k * 68 + (bq4 ^ (k & 12))] = st[j];
            }
        }
        __syncthreads();
        // prefetch next chunk (in flight during FMA)
        if (c + 1 < NCH) {
            if (GCH > 0 && (c + 1) < GCH) {
#pragma unroll
                for (int j = 0; j < 4; ++j)
                    st[j] = *(const float4*)(er + (c + 1) * 128 + (q + j * 8) * 4);
            } else {
                const int cc = c + 1;
                const int seg = cc >> 2;
                const float* sT = (seg == 0) ? s0T : (seg == 1) ? s1T : s2T;
#pragma unroll
                for (int j = 0; j < 4; ++j)
                    st[j] = *(const float4*)(sT + (size_t)((cc & 3) * 2048 + tid + j * 512) * 4);
            }
        }
        // FMA: 4 k's x NJ float4-b
        const int kx = (kq & 3) * 4;
#pragma unroll
        for (int ki = 0; ki < 4; ++ki) {
            const float* xr = XT + (kq * 4 + ki) * 68;
            float w = (ki == 0) ? wv[c].x : (ki == 1) ? wv[c].y
                    : (ki == 2) ? wv[c].z : wv[c].w;
#pragma unroll
            for (int j = 0; j < NJ; ++j) {
                int col = (bcol + 4 * j) ^ kx;
                fma4(acc[j], w, *(const float4*)(xr + col));
            }
        }
    }
}

// in-wave K-reduce over the wave's 4 kq values (tid bits 4,5)
__device__ __forceinline__ void waveRed(float4* acc, int n) {
#pragma unroll
    for (int j = 0; j < 8; ++j) {
        if (j >= n) break;
        float4 v = acc[j];
        v.x += __shfl_xor(v.x, 16); v.y += __shfl_xor(v.y, 16);
        v.z += __shfl_xor(v.z, 16); v.w += __shfl_xor(v.w, 16);
        v.x += __shfl_xor(v.x, 32); v.y += __shfl_xor(v.y, 32);
        v.z += __shfl_xor(v.z, 32); v.w += __shfl_xor(v.w, 32);
        acc[j] = v;
    }
}

// ---------------- per-batch attention (round-3 proven) -----------------------
__device__ __forceinline__ void attn_block(float* smem, int b, int tid,
                                           const float* __restrict__ ctx,
                                           const float* __restrict__ Wa,
                                           const float* __restrict__ h1n,
                                           float* __restrict__ cvecT,
                                           float* __restrict__ outAtt, int tstep)
{
    float* hcol = smem;          // [512]
    float* qL   = smem + 512;    // [512]
    float* pl   = smem + 1024;   // [64]
    float* scL  = smem + 1088;   // [64]
    hcol[tid] = h1n[(size_t)tid * 64 + b];
    __syncthreads();
    {
        int l = tid & 7;
#pragma unroll
        for (int rep = 0; rep < 8; ++rep) {
            int h = rep * 64 + (tid >> 3);
            const float* wr = Wa + (size_t)h * 512 + l * 4;
            float acc = 0.f;
#pragma unroll
            for (int it = 0; it < 16; ++it) {
                float4 wv = *(const float4*)(wr + it * 32);
                float4 hv = *(const float4*)&hcol[l * 4 + it * 32];
                acc = fmaf(wv.x, hv.x, acc);
                acc = fmaf(wv.y, hv.y, acc);
                acc = fmaf(wv.z, hv.z, acc);
                acc = fmaf(wv.w, hv.w, acc);
            }
            acc += __shfl_xor(acc, 1);
            acc += __shfl_xor(acc, 2);
            acc += __shfl_xor(acc, 4);
            if (l == 0) qL[h] = acc;
        }
    }
    __syncthreads();
    {
        int s = tid >> 3, l = tid & 7;
        const float* cr = ctx + ((size_t)s * 64 + b) * 512 + l * 4;
        float acc = 0.f;
#pragma unroll
        for (int it = 0; it < 16; ++it) {
            float4 cv = *(const float4*)(cr + it * 32);
            float4 qv = *(const float4*)&qL[l * 4 + it * 32];
            acc = fmaf(cv.x, qv.x, acc);
            acc = fmaf(cv.y, qv.y, acc);
            acc = fmaf(cv.z, qv.z, acc);
            acc = fmaf(cv.w, qv.w, acc);
        }
        acc += __shfl_xor(acc, 1);
        acc += __shfl_xor(acc, 2);
        acc += __shfl_xor(acc, 4);
        if (l == 0) scL[s] = acc;
    }
    __syncthreads();
    if (tid < 64) {
        float v = scL[tid];
        float m = v;
#pragma unroll
        for (int off = 32; off; off >>= 1) m = fmaxf(m, __shfl_xor(m, off));
        float e = __expf(v - m);
        float sum = e;
#pragma unroll
        for (int off = 32; off; off >>= 1) sum += __shfl_xor(sum, off);
        float p = e / sum;
        pl[tid] = p;
        outAtt[((size_t)tstep * 64 + b) * 64 + tid] = p;
    }
    __syncthreads();
    {
        const float* cp = ctx + (size_t)b * 512 + tid;
        float acc = 0.f;
#pragma unroll 8
        for (int s = 0; s < 64; ++s)
            acc = fmaf(pl[s], cp[(size_t)s * 32768], acc);
        pub(&cvecT[(size_t)tid * 64 + b], acc);
    }
}

// ---------------- the whole decoder: one persistent kernel -------------------
// 256 blocks x 512 threads, 1 block/CU. All weights pinned in VGPRs (112/thread)
// -> no per-step weight refetch; L2 keeps Wa+ctx resident.
__global__ __launch_bounds__(512, 2) void k_fused(
    const int* __restrict__ toks, const float* __restrict__ ctx,
    const float* __restrict__ emb,
    const float* __restrict__ Wih0, const float* __restrict__ Whh0,
    const float* __restrict__ bih0, const float* __restrict__ bhh0,
    const float* __restrict__ Wih1, const float* __restrict__ Whh1,
    const float* __restrict__ bih1, const float* __restrict__ bhh1,
    const float* __restrict__ Wa, const float* __restrict__ Wout,
    float* h0A, float* h1A, float* c0T, float* c1T,
    float* feedA, float* cvecA,
    float* outMain, float* outAtt, float* outHf, float* outCf, float* outFeedf,
    unsigned* barArr)
{
    __shared__ float XT[128 * 68];     // 34.8 KB staging tile (attn scratch aliases)
    __shared__ float GW[8 * 16 * 36];  // 18.4 KB cross-wave K-reduce
    __shared__ float GS[8 * 68];       // 2.2 KB gate sums
    unsigned* flags = barArr;
    unsigned* bar1  = barArr + NB;
    const int bid = blockIdx.x, tid = threadIdx.x;

    const int kq   = tid >> 4;          // 0..31
    const int rAB  = (tid >> 1) & 7;    // row within block (A/B): gate*2+hh
    const int bvAB = tid & 1;
    const int rD   = (tid >> 3) & 1;
    const int bvD  = tid & 7;
    const int rowgAB = (rAB >> 1) * 512 + 2 * bid + (rAB & 1);
    const int rowgD  = 2 * bid + rD;

    // -------- pin all weights in registers (loaded once) --------
    float4 wA[12], wB[8], wD[8];
#pragma unroll
    for (int c = 0; c < 12; ++c) {
        int kg = c * 128 + kq * 4;
        const float* p = (kg < 1024) ? (Wih0 + (size_t)rowgAB * 1024 + kg)
                                     : (Whh0 + (size_t)rowgAB * 512 + (kg - 1024));
        wA[c] = *(const float4*)p;
    }
#pragma unroll
    for (int c = 0; c < 8; ++c) {
        int kg = c * 128 + kq * 4;
        const float* p = (kg < 512) ? (Wih1 + (size_t)rowgAB * 512 + kg)
                                    : (Whh1 + (size_t)rowgAB * 512 + (kg - 512));
        wB[c] = *(const float4*)p;
    }
#pragma unroll
    for (int c = 0; c < 8; ++c)
        wD[c] = *(const float4*)(Wout + (size_t)rowgD * 1024 + c * 128 + kq * 4);

    // biases for the final-reduce thread's (r,b) output
    const int rFR = tid >> 6, gFR = rFR >> 1;
    const int hhFR = 2 * bid + (rFR & 1);
    const float biasA = bih0[gFR * 512 + hhFR] + bhh0[gFR * 512 + hhFR];
    const float biasB = bih1[gFR * 512 + hhFR] + bhh1[gFR * 512 + hhFR];

    float4 acc[8];
    unsigned g = 0;
    for (int t = 0; t < 32; ++t) {
        const float* h0c = h0A + (size_t)t * 32768;
        float*       h0n = h0A + (size_t)(t + 1) * 32768;
        const float* h1c = h1A + (size_t)t * 32768;
        float*       h1n = h1A + (size_t)(t + 1) * 32768;
        const float* fdc = feedA + (size_t)t * 32768;
        float*       fdn = feedA + (size_t)(t + 1) * 32768;
        float*       cvc = cvecA + (size_t)t * 32768;
        const float* er  = emb + (size_t)toks[t * 64 + (tid >> 3)] * 512;

        // ---------- Phase A: LSTM0 gates (K=1536 = [emb|feed|h0old]) ----------
#pragma unroll
        for (int j = 0; j < 8; ++j) acc[j] = {0.f, 0.f, 0.f, 0.f};
        gemm_phase<12, 4, 8>(XT, wA, acc, nullptr, fdc, h0c, er, tid, kq, bvAB * 32);
        waveRed(acc, 8);
        if (((tid >> 4) & 3) == 0) {
            float* gw = GW + ((tid >> 6) * 16 + (tid & 15)) * 36;
#pragma unroll
            for (int j = 0; j < 8; ++j) *(float4*)(gw + 4 * j) = acc[j];
        }
        __syncthreads();
        {   // final K-reduce over 8 waves -> biased gate sums
            int r = tid >> 6, b = tid & 63;
            int grp = r * 2 + (b >> 5), idx = b & 31;
            float v = biasA;
#pragma unroll
            for (int w = 0; w < 8; ++w) v += GW[(w * 16 + grp) * 36 + idx];
            GS[r * 68 + b] = v;
        }
        __syncthreads();
        if (tid < 128) {   // LSTM0 cell
            int hhl = tid >> 6, b = tid & 63;
            int hh = 2 * bid + hhl;
            float gi = GS[(0 + hhl) * 68 + b];
            float gf = GS[(2 + hhl) * 68 + b];
            float gg = GS[(4 + hhl) * 68 + b];
            float go = GS[(6 + hhl) * 68 + b];
            float c  = c0T[hh * 64 + b];
            float cn = sigm(gf) * c + sigm(gi) * tanh_(gg);
            float hn = sigm(go) * tanh_(cn);
            c0T[hh * 64 + b] = cn;
            pub(&h0n[hh * 64 + b], hn);
            if (t == 31) { outHf[b * 512 + hh] = hn; outCf[b * 512 + hh] = cn; }
        }
        gbar(flags, bar1, ++g);

        // ---------- Phase B: LSTM1 gates (K=1024 = [h0new|h1old]) ----------
#pragma unroll
        for (int j = 0; j < 8; ++j) acc[j] = {0.f, 0.f, 0.f, 0.f};
        gemm_phase<8, 0, 8>(XT, wB, acc, h0n, h1c, nullptr, nullptr, tid, kq, bvAB * 32);
        waveRed(acc, 8);
        if (((tid >> 4) & 3) == 0) {
            float* gw = GW + ((tid >> 6) * 16 + (tid & 15)) * 36;
#pragma unroll
            for (int j = 0; j < 8; ++j) *(float4*)(gw + 4 * j) = acc[j];
        }
        __syncthreads();
        {
            int r = tid >> 6, b = tid & 63;
            int grp = r * 2 + (b >> 5), idx = b & 31;
            float v = biasB;
#pragma unroll
            for (int w = 0; w < 8; ++w) v += GW[(w * 16 + grp) * 36 + idx];
            GS[r * 68 + b] = v;
        }
        __syncthreads();
        if (tid < 128) {   // LSTM1 cell
            int hhl = tid >> 6, b = tid & 63;
            int hh = 2 * bid + hhl;
            float gi = GS[(0 + hhl) * 68 + b];
            float gf = GS[(2 + hhl) * 68 + b];
            float gg = GS[(4 + hhl) * 68 + b];
            float go = GS[(6 + hhl) * 68 + b];
            float c  = c1T[hh * 64 + b];
            float cn = sigm(gf) * c + sigm(gi) * tanh_(gg);
            float hn = sigm(go) * tanh_(cn);
            c1T[hh * 64 + b] = cn;
            pub(&h1n[hh * 64 + b], hn);
            if (t == 31) { outHf[32768 + b * 512 + hh] = hn; outCf[32768 + b * 512 + hh] = cn; }
        }
        gbar(flags, bar1, ++g);

        // ---------- Phase C: attention (one block per batch elem) ----------
        if (bid < 64) attn_block(XT, bid, tid, ctx, Wa, h1n, cvc, outAtt, t);
        gbar(flags, bar1, ++g);

        // ---------- Phase D: out = tanh(Wout @ [cvec|h1new]) ----------
        acc[0] = {0.f, 0.f, 0.f, 0.f};
        acc[1] = {0.f, 0.f, 0.f, 0.f};
        gemm_phase<8, 0, 2>(XT, wD, acc, cvc, h1n, nullptr, nullptr, tid, kq, bvD * 8);
        waveRed(acc, 2);
        if (((tid >> 4) & 3) == 0) {
            float* gw = GW + ((tid >> 6) * 16 + (tid & 15)) * 36;
            *(float4*)(gw)     = acc[0];
            *(float4*)(gw + 4) = acc[1];
        }
        __syncthreads();
        if (tid < 128) {
            int rr = tid >> 6, b = tid & 63;
            int grp = rr * 8 + (b >> 3), idx = b & 7;
            float v = 0.f;
#pragma unroll
            for (int w = 0; w < 8; ++w) v += GW[(w * 16 + grp) * 36 + idx];
            float ah = tanh_(v);
            int o = 2 * bid + rr;
            outMain[((size_t)t * 64 + b) * 512 + o] = ah;
            pub(&fdn[o * 64 + b], ah);
            if (t == 31) outFeedf[b * 512 + o] = ah;
        }
        gbar(flags, bar1, ++g);
    }
}

extern "C" void kernel_launch(void* const* d_in, const int* in_sizes, int n_in,
                              void* d_out, int out_size, void* d_ws, size_t ws_size,
                              hipStream_t stream) {
    const int*   toks  = (const int*)d_in[0];
    const float* ctx   = (const float*)d_in[2];
    const float* h0i   = (const float*)d_in[3];
    const float* c0i   = (const float*)d_in[4];
    const float* feedi = (const float*)d_in[5];
    const float* emb   = (const float*)d_in[6];
    const float* Wih0  = (const float*)d_in[7];
    const float* Whh0  = (const float*)d_in[8];
    const float* bih0  = (const float*)d_in[9];
    const float* bhh0  = (const float*)d_in[10];
    const float* Wih1  = (const float*)d_in[11];
    const float* Whh1  = (const float*)d_in[12];
    const float* bih1  = (const float*)d_in[13];
    const float* bhh1  = (const float*)d_in[14];
    const float* Wa    = (const float*)d_in[15];
    const float* Wout  = (const float*)d_in[16];

    // workspace: write-once arenas + block-private c-state + barrier flags
    float* ws    = (float*)d_ws;
    float* h0A   = ws;                    // 33 * 32768
    float* h1A   = h0A + 33 * 32768;      // 33 * 32768
    float* feedA = h1A + 33 * 32768;      // 33 * 32768
    float* cvecA = feedA + 33 * 32768;    // 32 * 32768
    float* c0T   = cvecA + 32 * 32768;    // 32768
    float* c1T   = c0T + 32768;           // 32768
    unsigned* barArr = (unsigned*)(c1T + 32768);  // flags[256] + bar1

    float* out      = (float*)d_out;
    float* outMain  = out;             // [T,B,H]
    float* outAtt   = out + 1048576;   // [T,B,S]
    float* outHf    = out + 1179648;   // [L,B,H]
    float* outCf    = out + 1245184;   // [L,B,H]
    float* outFeedf = out + 1310720;   // [B,H]

    hipLaunchKernelGGL(k_init, dim3(128), dim3(256), 0, stream,
                       h0i, c0i, feedi, h0A, h1A, c0T, c1T, feedA, barArr);

    hipLaunchKernelGGL(k_fused, dim3(NB), dim3(512), 0, stream,
                       toks, ctx, emb, Wih0, Whh0, bih0, bhh0,
                       Wih1, Whh1, bih1, bhh1, Wa, Wout,
                       h0A, h1A, c0T, c1T, feedA, cvecA,
                       outMain, outAtt, outHf, outCf, outFeedf, barArr);
}

// Round 5
// 2960.994 us; speedup vs baseline: 1.5862x; 1.5862x over previous
//
#include <hip/hip_runtime.h>
#include <cstdint>

#define NB 256

__device__ __forceinline__ float sigm(float x) { return 1.f / (1.f + __expf(-x)); }
__device__ __forceinline__ float tanh_(float x) { return 1.f - 2.f / (1.f + __expf(2.f * x)); }

__device__ __forceinline__ void fma4(float4& a, float s, const float4& x) {
    a.x = fmaf(s, x.x, a.x); a.y = fmaf(s, x.y, a.y);
    a.z = fmaf(s, x.z, a.z); a.w = fmaf(s, x.w, a.w);
}

// publish a float to the LLC (coherence point) via agent-scope store.
__device__ __forceinline__ void pub(float* p, float v) {
    __hip_atomic_store(p, v, __ATOMIC_RELAXED, __HIP_MEMORY_SCOPE_AGENT);
}

// ---------------- grid barrier (round-3 proven: no cache-invalidating fences) -
__device__ __forceinline__ void gbar(unsigned* flags, unsigned* bar1, unsigned g) {
    asm volatile("s_waitcnt vmcnt(0)" ::: "memory");  // this wave's pub stores at LLC
    __syncthreads();
    const int tid = threadIdx.x, bid = blockIdx.x;
    if (bid == 0) {
        if (tid > 0 && tid < NB) {
            while (__hip_atomic_load(&flags[tid], __ATOMIC_RELAXED,
                                     __HIP_MEMORY_SCOPE_AGENT) < g)
                __builtin_amdgcn_s_sleep(2);
        }
        __syncthreads();
        if (tid == 0)
            __hip_atomic_store(bar1, g, __ATOMIC_RELAXED, __HIP_MEMORY_SCOPE_AGENT);
    } else if (tid == 0) {
        __hip_atomic_store(&flags[bid], g, __ATOMIC_RELAXED, __HIP_MEMORY_SCOPE_AGENT);
        while (__hip_atomic_load(bar1, __ATOMIC_RELAXED,
                                 __HIP_MEMORY_SCOPE_AGENT) < g)
            __builtin_amdgcn_s_sleep(2);
    }
    __syncthreads();
}

// ---------------- init: states into transposed [h][b] slot-0 arenas ----------
__global__ __launch_bounds__(256) void k_init(const float* __restrict__ h0i,
                                              const float* __restrict__ c0i,
                                              const float* __restrict__ feedi,
                                              float* h0A, float* h1A, float* c0T, float* c1T,
                                              float* feedA, unsigned* barArr) {
    int t = blockIdx.x * 256 + threadIdx.x;  // 32768 = 512*64
    if (t < NB + 1) barArr[t] = 0u;          // flags[0..255] + bar1
    int hh = t >> 6, b = t & 63;
    h0A[t]   = h0i[b * 512 + hh];
    h1A[t]   = h0i[32768 + b * 512 + hh];
    c0T[t]   = c0i[b * 512 + hh];
    c1T[t]   = c0i[32768 + b * 512 + hh];
    feedA[t] = feedi[b * 512 + hh];
}

// ---------------- LDS-weight GEMM phase --------------------------------------
// Thread (kq = tid>>4, grp = tid&15) owns 1 row x 4 k's per 128-k chunk; its
// weights live in LDS at wrow (stride 128 floats per chunk) — loaded ONCE at
// kernel start, immune to barrier memory-clobbers and register pressure.
// X staged chunk-wise into XT[k][b] with XOR swizzle col = b ^ (k&12).
// Partial acc covers b = bcol..bcol+4*NJ-1; K-reduce done by caller.
template<int NCH, int GCH, int NJ>
__device__ __forceinline__ void gemm_phase(
    float* XT, const float* wrow, float4* acc,
    const float* s0T, const float* s1T, const float* s2T,
    const float* er, const int tid, const int kq, const int bcol)
{
    float4 st[4];
    const int q = tid & 7;
    // prefetch chunk 0
    if (GCH > 0) {
#pragma unroll
        for (int j = 0; j < 4; ++j)
            st[j] = *(const float4*)(er + (q + j * 8) * 4);
    } else {
#pragma unroll
        for (int j = 0; j < 4; ++j)
            st[j] = *(const float4*)(s0T + (size_t)(tid + j * 512) * 4);
    }
#pragma unroll
    for (int c = 0; c < NCH; ++c) {
        __syncthreads();   // previous XT/LDS consumers done
        if (GCH > 0 && c < GCH) {
            const int b = tid >> 3;
#pragma unroll
            for (int j = 0; j < 4; ++j) {
                int kl = (q + j * 8) * 4;
                int col = b ^ (kl & 12);   // (kl+i)&12 == kl&12 for i<4
                XT[(kl + 0) * 68 + col] = st[j].x;
                XT[(kl + 1) * 68 + col] = st[j].y;
                XT[(kl + 2) * 68 + col] = st[j].z;
                XT[(kl + 3) * 68 + col] = st[j].w;
            }
        } else {
#pragma unroll
            for (int j = 0; j < 4; ++j) {
                int f = tid + j * 512;
                int k = f >> 4, bq4 = (f & 15) * 4;
                *(float4*)&XT[k * 68 + (bq4 ^ (k & 12))] = st[j];
            }
        }
        __syncthreads();
        // prefetch next chunk (in flight during FMA)
        if (c + 1 < NCH) {
            if (GCH > 0 && (c + 1) < GCH) {
#pragma unroll
                for (int j = 0; j < 4; ++j)
                    st[j] = *(const float4*)(er + (c + 1) * 128 + (q + j * 8) * 4);
            } else {
                const int cc = c + 1;
                const int seg = cc >> 2;
                const float* sT = (seg == 0) ? s0T : (seg == 1) ? s1T : s2T;
#pragma unroll
                for (int j = 0; j < 4; ++j)
                    st[j] = *(const float4*)(sT + (size_t)((cc & 3) * 2048 + tid + j * 512) * 4);
            }
        }
        // W for this chunk from LDS (broadcast across the 16 lanes sharing kq)
        float4 w = *(const float4*)(wrow + c * 128);
        // FMA: 4 k's x NJ float4-b
        const int kx = (kq & 3) * 4;
#pragma unroll
        for (int ki = 0; ki < 4; ++ki) {
            const float* xr = XT + (kq * 4 + ki) * 68;
            float ws = (ki == 0) ? w.x : (ki == 1) ? w.y : (ki == 2) ? w.z : w.w;
#pragma unroll
            for (int j = 0; j < NJ; ++j) {
                int col = (bcol + 4 * j) ^ kx;
                fma4(acc[j], ws, *(const float4*)(xr + col));
            }
        }
    }
}

// in-wave K-reduce over the wave's 4 kq values (tid bits 4,5)
__device__ __forceinline__ void waveRed(float4* acc, int n) {
#pragma unroll
    for (int j = 0; j < 8; ++j) {
        if (j >= n) break;
        float4 v = acc[j];
        v.x += __shfl_xor(v.x, 16); v.y += __shfl_xor(v.y, 16);
        v.z += __shfl_xor(v.z, 16); v.w += __shfl_xor(v.w, 16);
        v.x += __shfl_xor(v.x, 32); v.y += __shfl_xor(v.y, 32);
        v.z += __shfl_xor(v.z, 32); v.w += __shfl_xor(v.w, 32);
        acc[j] = v;
    }
}

// ---------------- per-batch attention (round-3 proven) -----------------------
__device__ __forceinline__ void attn_block(float* smem, int b, int tid,
                                           const float* __restrict__ ctx,
                                           const float* __restrict__ Wa,
                                           const float* __restrict__ h1n,
                                           float* __restrict__ cvecT,
                                           float* __restrict__ outAtt, int tstep)
{
    float* hcol = smem;          // [512]
    float* qL   = smem + 512;    // [512]
    float* pl   = smem + 1024;   // [64]
    float* scL  = smem + 1088;   // [64]
    hcol[tid] = h1n[(size_t)tid * 64 + b];
    __syncthreads();
    {
        int l = tid & 7;
#pragma unroll
        for (int rep = 0; rep < 8; ++rep) {
            int h = rep * 64 + (tid >> 3);
            const float* wr = Wa + (size_t)h * 512 + l * 4;
            float acc = 0.f;
#pragma unroll
            for (int it = 0; it < 16; ++it) {
                float4 wv = *(const float4*)(wr + it * 32);
                float4 hv = *(const float4*)&hcol[l * 4 + it * 32];
                acc = fmaf(wv.x, hv.x, acc);
                acc = fmaf(wv.y, hv.y, acc);
                acc = fmaf(wv.z, hv.z, acc);
                acc = fmaf(wv.w, hv.w, acc);
            }
            acc += __shfl_xor(acc, 1);
            acc += __shfl_xor(acc, 2);
            acc += __shfl_xor(acc, 4);
            if (l == 0) qL[h] = acc;
        }
    }
    __syncthreads();
    {
        int s = tid >> 3, l = tid & 7;
        const float* cr = ctx + ((size_t)s * 64 + b) * 512 + l * 4;
        float acc = 0.f;
#pragma unroll
        for (int it = 0; it < 16; ++it) {
            float4 cv = *(const float4*)(cr + it * 32);
            float4 qv = *(const float4*)&qL[l * 4 + it * 32];
            acc = fmaf(cv.x, qv.x, acc);
            acc = fmaf(cv.y, qv.y, acc);
            acc = fmaf(cv.z, qv.z, acc);
            acc = fmaf(cv.w, qv.w, acc);
        }
        acc += __shfl_xor(acc, 1);
        acc += __shfl_xor(acc, 2);
        acc += __shfl_xor(acc, 4);
        if (l == 0) scL[s] = acc;
    }
    __syncthreads();
    if (tid < 64) {
        float v = scL[tid];
        float m = v;
#pragma unroll
        for (int off = 32; off; off >>= 1) m = fmaxf(m, __shfl_xor(m, off));
        float e = __expf(v - m);
        float sum = e;
#pragma unroll
        for (int off = 32; off; off >>= 1) sum += __shfl_xor(sum, off);
        float p = e / sum;
        pl[tid] = p;
        outAtt[((size_t)tstep * 64 + b) * 64 + tid] = p;
    }
    __syncthreads();
    {
        const float* cp = ctx + (size_t)b * 512 + tid;
        float acc = 0.f;
#pragma unroll 8
        for (int s = 0; s < 64; ++s)
            acc = fmaf(pl[s], cp[(size_t)s * 32768], acc);
        pub(&cvecT[(size_t)tid * 64 + b], acc);
    }
}

// ---------------- the whole decoder: one persistent kernel -------------------
// 256 blocks x 512 threads, 1 block/CU (forced by 145.5 KB LDS). Each block's
// weight rows live in LDS, loaded once -> zero per-step weight refetch, no
// register pressure, no barrier-clobber rematerialization.
__global__ __launch_bounds__(512, 1) void k_fused(
    const int* __restrict__ toks, const float* __restrict__ ctx,
    const float* __restrict__ emb,
    const float* __restrict__ Wih0, const float* __restrict__ Whh0,
    const float* __restrict__ bih0, const float* __restrict__ bhh0,
    const float* __restrict__ Wih1, const float* __restrict__ Whh1,
    const float* __restrict__ bih1, const float* __restrict__ bhh1,
    const float* __restrict__ Wa, const float* __restrict__ Wout,
    float* h0A, float* h1A, float* c0T, float* c1T,
    float* feedA, float* cvecA,
    float* outMain, float* outAtt, float* outHf, float* outCf, float* outFeedf,
    unsigned* barArr)
{
    __shared__ float WA[8 * 1536];     // 48 KB  LSTM0 rows [emb|feed|h0 : 1536]
    __shared__ float WB[8 * 1024];     // 32 KB  LSTM1 rows [h0n|h1 : 1024]
    __shared__ float WD[2 * 1024];     // 8 KB   Wout rows  [cvec|h1n : 1024]
    __shared__ float XT[128 * 68];     // 34.8 KB staging tile (attn scratch aliases)
    __shared__ float GW[8 * 16 * 36];  // 18.4 KB cross-wave K-reduce
    __shared__ float GS[8 * 68];       // 2.2 KB gate sums
    unsigned* flags = barArr;
    unsigned* bar1  = barArr + NB;
    const int bid = blockIdx.x, tid = threadIdx.x;

    const int kq   = tid >> 4;          // 0..31
    const int rAB  = (tid >> 1) & 7;    // row within block (A/B): gate*2+hh
    const int bvAB = tid & 1;
    const int rD   = (tid >> 3) & 1;
    const int bvD  = tid & 7;

    // -------- load this block's weight rows into LDS (once) --------
#pragma unroll
    for (int r = 0; r < 8; ++r) {
        int rowg = (r >> 1) * 512 + 2 * bid + (r & 1);
        if (tid < 384) {
            int k4 = tid * 4;
            float4 v = (k4 < 1024)
                ? *(const float4*)(Wih0 + (size_t)rowg * 1024 + k4)
                : *(const float4*)(Whh0 + (size_t)rowg * 512 + (k4 - 1024));
            *(float4*)&WA[r * 1536 + k4] = v;
        }
        if (tid < 256) {
            int k4 = tid * 4;
            float4 v = (k4 < 512)
                ? *(const float4*)(Wih1 + (size_t)rowg * 512 + k4)
                : *(const float4*)(Whh1 + (size_t)rowg * 512 + (k4 - 512));
            *(float4*)&WB[r * 1024 + k4] = v;
        }
    }
    {
        int r = tid >> 8, k4 = (tid & 255) * 4;
        *(float4*)&WD[r * 1024 + k4] =
            *(const float4*)(Wout + (size_t)(2 * bid + r) * 1024 + k4);
    }

    const float* wlA = WA + rAB * 1536 + kq * 4;
    const float* wlB = WB + rAB * 1024 + kq * 4;
    const float* wlD = WD + rD  * 1024 + kq * 4;

    // biases for the final-reduce thread's (r,b) output
    const int rFR = tid >> 6, gFR = rFR >> 1;
    const int hhFR = 2 * bid + (rFR & 1);
    const float biasA = bih0[gFR * 512 + hhFR] + bhh0[gFR * 512 + hhFR];
    const float biasB = bih1[gFR * 512 + hhFR] + bhh1[gFR * 512 + hhFR];

    float4 acc[8];
    unsigned g = 0;
    for (int t = 0; t < 32; ++t) {
        const float* h0c = h0A + (size_t)t * 32768;
        float*       h0n = h0A + (size_t)(t + 1) * 32768;
        const float* h1c = h1A + (size_t)t * 32768;
        float*       h1n = h1A + (size_t)(t + 1) * 32768;
        const float* fdc = feedA + (size_t)t * 32768;
        float*       fdn = feedA + (size_t)(t + 1) * 32768;
        float*       cvc = cvecA + (size_t)t * 32768;
        const float* er  = emb + (size_t)toks[t * 64 + (tid >> 3)] * 512;

        // ---------- Phase A: LSTM0 gates (K=1536 = [emb|feed|h0old]) ----------
#pragma unroll
        for (int j = 0; j < 8; ++j) acc[j] = {0.f, 0.f, 0.f, 0.f};
        gemm_phase<12, 4, 8>(XT, wlA, acc, nullptr, fdc, h0c, er, tid, kq, bvAB * 32);
        waveRed(acc, 8);
        if (((tid >> 4) & 3) == 0) {
            float* gw = GW + ((tid >> 6) * 16 + (tid & 15)) * 36;
#pragma unroll
            for (int j = 0; j < 8; ++j) *(float4*)(gw + 4 * j) = acc[j];
        }
        __syncthreads();
        {   // final K-reduce over 8 waves -> biased gate sums
            int r = tid >> 6, b = tid & 63;
            int grp = r * 2 + (b >> 5), idx = b & 31;
            float v = biasA;
#pragma unroll
            for (int w = 0; w < 8; ++w) v += GW[(w * 16 + grp) * 36 + idx];
            GS[r * 68 + b] = v;
        }
        __syncthreads();
        if (tid < 128) {   // LSTM0 cell
            int hhl = tid >> 6, b = tid & 63;
            int hh = 2 * bid + hhl;
            float gi = GS[(0 + hhl) * 68 + b];
            float gf = GS[(2 + hhl) * 68 + b];
            float gg = GS[(4 + hhl) * 68 + b];
            float go = GS[(6 + hhl) * 68 + b];
            float c  = c0T[hh * 64 + b];
            float cn = sigm(gf) * c + sigm(gi) * tanh_(gg);
            float hn = sigm(go) * tanh_(cn);
            c0T[hh * 64 + b] = cn;
            pub(&h0n[hh * 64 + b], hn);
            if (t == 31) { outHf[b * 512 + hh] = hn; outCf[b * 512 + hh] = cn; }
        }
        gbar(flags, bar1, ++g);

        // ---------- Phase B: LSTM1 gates (K=1024 = [h0new|h1old]) ----------
#pragma unroll
        for (int j = 0; j < 8; ++j) acc[j] = {0.f, 0.f, 0.f, 0.f};
        gemm_phase<8, 0, 8>(XT, wlB, acc, h0n, h1c, nullptr, nullptr, tid, kq, bvAB * 32);
        waveRed(acc, 8);
        if (((tid >> 4) & 3) == 0) {
            float* gw = GW + ((tid >> 6) * 16 + (tid & 15)) * 36;
#pragma unroll
            for (int j = 0; j < 8; ++j) *(float4*)(gw + 4 * j) = acc[j];
        }
        __syncthreads();
        {
            int r = tid >> 6, b = tid & 63;
            int grp = r * 2 + (b >> 5), idx = b & 31;
            float v = biasB;
#pragma unroll
            for (int w = 0; w < 8; ++w) v += GW[(w * 16 + grp) * 36 + idx];
            GS[r * 68 + b] = v;
        }
        __syncthreads();
        if (tid < 128) {   // LSTM1 cell
            int hhl = tid >> 6, b = tid & 63;
            int hh = 2 * bid + hhl;
            float gi = GS[(0 + hhl) * 68 + b];
            float gf = GS[(2 + hhl) * 68 + b];
            float gg = GS[(4 + hhl) * 68 + b];
            float go = GS[(6 + hhl) * 68 + b];
            float c  = c1T[hh * 64 + b];
            float cn = sigm(gf) * c + sigm(gi) * tanh_(gg);
            float hn = sigm(go) * tanh_(cn);
            c1T[hh * 64 + b] = cn;
            pub(&h1n[hh * 64 + b], hn);
            if (t == 31) { outHf[32768 + b * 512 + hh] = hn; outCf[32768 + b * 512 + hh] = cn; }
        }
        gbar(flags, bar1, ++g);

        // ---------- Phase C: attention (one block per batch elem) ----------
        if (bid < 64) attn_block(XT, bid, tid, ctx, Wa, h1n, cvc, outAtt, t);
        gbar(flags, bar1, ++g);

        // ---------- Phase D: out = tanh(Wout @ [cvec|h1new]) ----------
        acc[0] = {0.f, 0.f, 0.f, 0.f};
        acc[1] = {0.f, 0.f, 0.f, 0.f};
        gemm_phase<8, 0, 2>(XT, wlD, acc, cvc, h1n, nullptr, nullptr, tid, kq, bvD * 8);
        waveRed(acc, 2);
        if (((tid >> 4) & 3) == 0) {
            float* gw = GW + ((tid >> 6) * 16 + (tid & 15)) * 36;
            *(float4*)(gw)     = acc[0];
            *(float4*)(gw + 4) = acc[1];
        }
        __syncthreads();
        if (tid < 128) {
            int rr = tid >> 6, b = tid & 63;
            int grp = rr * 8 + (b >> 3), idx = b & 7;
            float v = 0.f;
#pragma unroll
            for (int w = 0; w < 8; ++w) v += GW[(w * 16 + grp) * 36 + idx];
            float ah = tanh_(v);
            int o = 2 * bid + rr;
            outMain[((size_t)t * 64 + b) * 512 + o] = ah;
            pub(&fdn[o * 64 + b], ah);
            if (t == 31) outFeedf[b * 512 + o] = ah;
        }
        gbar(flags, bar1, ++g);
    }
}

extern "C" void kernel_launch(void* const* d_in, const int* in_sizes, int n_in,
                              void* d_out, int out_size, void* d_ws, size_t ws_size,
                              hipStream_t stream) {
    const int*   toks  = (const int*)d_in[0];
    const float* ctx   = (const float*)d_in[2];
    const float* h0i   = (const float*)d_in[3];
    const float* c0i   = (const float*)d_in[4];
    const float* feedi = (const float*)d_in[5];
    const float* emb   = (const float*)d_in[6];
    const float* Wih0  = (const float*)d_in[7];
    const float* Whh0  = (const float*)d_in[8];
    const float* bih0  = (const float*)d_in[9];
    const float* bhh0  = (const float*)d_in[10];
    const float* Wih1  = (const float*)d_in[11];
    const float* Whh1  = (const float*)d_in[12];
    const float* bih1  = (const float*)d_in[13];
    const float* bhh1  = (const float*)d_in[14];
    const float* Wa    = (const float*)d_in[15];
    const float* Wout  = (const float*)d_in[16];

    // workspace: write-once arenas + block-private c-state + barrier flags
    float* ws    = (float*)d_ws;
    float* h0A   = ws;                    // 33 * 32768
    float* h1A   = h0A + 33 * 32768;      // 33 * 32768
    float* feedA = h1A + 33 * 32768;      // 33 * 32768
    float* cvecA = feedA + 33 * 32768;    // 32 * 32768
    float* c0T   = cvecA + 32 * 32768;    // 32768
    float* c1T   = c0T + 32768;           // 32768
    unsigned* barArr = (unsigned*)(c1T + 32768);  // flags[256] + bar1

    float* out      = (float*)d_out;
    float* outMain  = out;             // [T,B,H]
    float* outAtt   = out + 1048576;   // [T,B,S]
    float* outHf    = out + 1179648;   // [L,B,H]
    float* outCf    = out + 1245184;   // [L,B,H]
    float* outFeedf = out + 1310720;   // [B,H]

    hipLaunchKernelGGL(k_init, dim3(128), dim3(256), 0, stream,
                       h0i, c0i, feedi, h0A, h1A, c0T, c1T, feedA, barArr);

    hipLaunchKernelGGL(k_fused, dim3(NB), dim3(512), 0, stream,
                       toks, ctx, emb, Wih0, Whh0, bih0, bhh0,
                       Wih1, Whh1, bih1, bhh1, Wa, Wout,
                       h0A, h1A, c0T, c1T, feedA, cvecA,
                       outMain, outAtt, outHf, outCf, outFeedf, barArr);
}

// Round 6
// 2467.837 us; speedup vs baseline: 1.9032x; 1.1998x over previous
//
#include <hip/hip_runtime.h>
#include <cstdint>

#define NB 256
#define FSTR 32   // u32 stride per barrier line (128 B) — one LLC line per word

__device__ __forceinline__ float sigm(float x) { return 1.f / (1.f + __expf(-x)); }
__device__ __forceinline__ float tanh_(float x) { return 1.f - 2.f / (1.f + __expf(2.f * x)); }

__device__ __forceinline__ void fma4(float4& a, float s, const float4& x) {
    a.x = fmaf(s, x.x, a.x); a.y = fmaf(s, x.y, a.y);
    a.z = fmaf(s, x.z, a.z); a.w = fmaf(s, x.w, a.w);
}

// publish two packed floats (8 B) to the LLC coherence point.
__device__ __forceinline__ void pub2(float* p, float a, float b) {
    unsigned long long u = ((unsigned long long)__float_as_uint(b) << 32) |
                           (unsigned long long)__float_as_uint(a);
    __hip_atomic_store((unsigned long long*)p, u, __ATOMIC_RELAXED,
                       __HIP_MEMORY_SCOPE_AGENT);
}

__device__ __forceinline__ unsigned ldf(const unsigned* p) {
    return __hip_atomic_load(p, __ATOMIC_RELAXED, __HIP_MEMORY_SCOPE_AGENT);
}
__device__ __forceinline__ void stf(unsigned* p, unsigned v) {
    __hip_atomic_store(p, v, __ATOMIC_RELAXED, __HIP_MEMORY_SCOPE_AGENT);
}

// ---------------- grid barrier: line-padded flags, replicated release, backoff
// flags[bid]: one 128B line each. rel: 32 copies on separate lines; poller
// bid polls copy (bid&31) -> <=8 pollers/line at >=0.43us period. No
// cache-invalidating fences (write-once + LLC-publish protocol, r3-proven).
__device__ __forceinline__ void gbar(unsigned* flags, unsigned* rel, unsigned g) {
    asm volatile("s_waitcnt vmcnt(0)" ::: "memory");  // pub stores at LLC
    __syncthreads();
    const int tid = threadIdx.x, bid = blockIdx.x;
    if (bid == 0) {
        if (tid >= 1 && tid < NB) {
            const unsigned* f = flags + tid * FSTR;
            if (ldf(f) < g) { __builtin_amdgcn_s_sleep(4);
              if (ldf(f) < g) { __builtin_amdgcn_s_sleep(8);
                while (ldf(f) < g) __builtin_amdgcn_s_sleep(16); } }
        }
        __syncthreads();  // all arrivals observed
        if (tid < 32) stf(rel + tid * FSTR, g);
    } else if (tid == 0) {
        stf(flags + bid * FSTR, g);
        const unsigned* r = rel + (bid & 31) * FSTR;
        if (ldf(r) < g) { __builtin_amdgcn_s_sleep(4);
          if (ldf(r) < g) { __builtin_amdgcn_s_sleep(8);
            while (ldf(r) < g) __builtin_amdgcn_s_sleep(16); } }
    }
    __syncthreads();
}

// ---------------- init: states into transposed [h][b] slot-0 arenas ----------
__global__ __launch_bounds__(256) void k_init(const float* __restrict__ h0i,
                                              const float* __restrict__ c0i,
                                              const float* __restrict__ feedi,
                                              float* h0A, float* h1A, float* c0T, float* c1T,
                                              float* feedA, unsigned* barArr) {
    int t = blockIdx.x * 256 + threadIdx.x;  // 32768 = 512*64
    if (t < (NB + 32) * FSTR) barArr[t] = 0u;  // flags[256] + rel[32], line-padded
    int hh = t >> 6, b = t & 63;
    h0A[t]   = h0i[b * 512 + hh];
    h1A[t]   = h0i[32768 + b * 512 + hh];
    c0T[t]   = c0i[b * 512 + hh];
    c1T[t]   = c0i[32768 + b * 512 + hh];
    feedA[t] = feedi[b * 512 + hh];
}

// ---------------- LDS-weight GEMM phase --------------------------------------
// Thread (kq = tid>>4, grp = tid&15) owns 1 row x 4 k's per 128-k chunk; its
// weights live in LDS at wrow (stride 128 floats per chunk) — loaded ONCE.
// X staged chunk-wise into XT[k][b] with XOR swizzle col = b ^ (k&12).
// First GCH chunks gather from per-thread row pointer `er` (row-major [b][K']:
// embedding rows OR the [b][512] cvec slot); rest read linear [k][b] segments.
template<int NCH, int GCH, int NJ>
__device__ __forceinline__ void gemm_phase(
    float* XT, const float* wrow, float4* acc,
    const float* s0T, const float* s1T, const float* s2T,
    const float* er, const int tid, const int kq, const int bcol)
{
    float4 st[4];
    const int q = tid & 7;
    // prefetch chunk 0
    if (GCH > 0) {
#pragma unroll
        for (int j = 0; j < 4; ++j)
            st[j] = *(const float4*)(er + (q + j * 8) * 4);
    } else {
#pragma unroll
        for (int j = 0; j < 4; ++j)
            st[j] = *(const float4*)(s0T + (size_t)(tid + j * 512) * 4);
    }
#pragma unroll
    for (int c = 0; c < NCH; ++c) {
        __syncthreads();   // previous XT/LDS consumers done
        if (GCH > 0 && c < GCH) {
            const int b = tid >> 3;
#pragma unroll
            for (int j = 0; j < 4; ++j) {
                int kl = (q + j * 8) * 4;
                int col = b ^ (kl & 12);   // (kl+i)&12 == kl&12 for i<4
                XT[(kl + 0) * 68 + col] = st[j].x;
                XT[(kl + 1) * 68 + col] = st[j].y;
                XT[(kl + 2) * 68 + col] = st[j].z;
                XT[(kl + 3) * 68 + col] = st[j].w;
            }
        } else {
#pragma unroll
            for (int j = 0; j < 4; ++j) {
                int f = tid + j * 512;
                int k = f >> 4, bq4 = (f & 15) * 4;
                *(float4*)&XT[k * 68 + (bq4 ^ (k & 12))] = st[j];
            }
        }
        __syncthreads();
        // prefetch next chunk (in flight during FMA)
        if (c + 1 < NCH) {
            if (GCH > 0 && (c + 1) < GCH) {
#pragma unroll
                for (int j = 0; j < 4; ++j)
                    st[j] = *(const float4*)(er + (c + 1) * 128 + (q + j * 8) * 4);
            } else {
                const int cc = c + 1;
                const int seg = cc >> 2;
                const float* sT = (seg == 0) ? s0T : (seg == 1) ? s1T : s2T;
#pragma unroll
                for (int j = 0; j < 4; ++j)
                    st[j] = *(const float4*)(sT + (size_t)((cc & 3) * 2048 + tid + j * 512) * 4);
            }
        }
        // W for this chunk from LDS (broadcast across the 16 lanes sharing kq)
        float4 w = *(const float4*)(wrow + c * 128);
        const int kx = (kq & 3) * 4;
#pragma unroll
        for (int ki = 0; ki < 4; ++ki) {
            const float* xr = XT + (kq * 4 + ki) * 68;
            float ws = (ki == 0) ? w.x : (ki == 1) ? w.y : (ki == 2) ? w.z : w.w;
#pragma unroll
            for (int j = 0; j < NJ; ++j) {
                int col = (bcol + 4 * j) ^ kx;
                fma4(acc[j], ws, *(const float4*)(xr + col));
            }
        }
    }
}

// in-wave K-reduce over the wave's 4 kq values (tid bits 4,5)
__device__ __forceinline__ void waveRed(float4* acc, int n) {
#pragma unroll
    for (int j = 0; j < 8; ++j) {
        if (j >= n) break;
        float4 v = acc[j];
        v.x += __shfl_xor(v.x, 16); v.y += __shfl_xor(v.y, 16);
        v.z += __shfl_xor(v.z, 16); v.w += __shfl_xor(v.w, 16);
        v.x += __shfl_xor(v.x, 32); v.y += __shfl_xor(v.y, 32);
        v.z += __shfl_xor(v.z, 32); v.w += __shfl_xor(v.w, 32);
        acc[j] = v;
    }
}

// ---------------- per-batch attention; cvec published coalesced [b][512] -----
__device__ __forceinline__ void attn_block(float* smem, int b, int tid,
                                           const float* __restrict__ ctx,
                                           const float* __restrict__ Wa,
                                           const float* __restrict__ h1n,
                                           float* __restrict__ cvB,
                                           float* __restrict__ outAtt, int tstep)
{
    float* hcol = smem;          // [512]
    float* qL   = smem + 512;    // [512]  (reused as cvL later)
    float* pl   = smem + 1024;   // [64]
    float* scL  = smem + 1088;   // [64]
    hcol[tid] = h1n[(size_t)tid * 64 + b];
    __syncthreads();
    {   // q[h] = dot(Wa[h,:], hcol)
        int l = tid & 7;
#pragma unroll
        for (int rep = 0; rep < 8; ++rep) {
            int h = rep * 64 + (tid >> 3);
            const float* wr = Wa + (size_t)h * 512 + l * 4;
            float acc = 0.f;
#pragma unroll
            for (int it = 0; it < 16; ++it) {
                float4 wv = *(const float4*)(wr + it * 32);
                float4 hv = *(const float4*)&hcol[l * 4 + it * 32];
                acc = fmaf(wv.x, hv.x, acc);
                acc = fmaf(wv.y, hv.y, acc);
                acc = fmaf(wv.z, hv.z, acc);
                acc = fmaf(wv.w, hv.w, acc);
            }
            acc += __shfl_xor(acc, 1);
            acc += __shfl_xor(acc, 2);
            acc += __shfl_xor(acc, 4);
            if (l == 0) qL[h] = acc;
        }
    }
    __syncthreads();
    {   // scores[s] = dot(q, ctx[s,b,:])
        int s = tid >> 3, l = tid & 7;
        const float* cr = ctx + ((size_t)s * 64 + b) * 512 + l * 4;
        float acc = 0.f;
#pragma unroll
        for (int it = 0; it < 16; ++it) {
            float4 cv = *(const float4*)(cr + it * 32);
            float4 qv = *(const float4*)&qL[l * 4 + it * 32];
            acc = fmaf(cv.x, qv.x, acc);
            acc = fmaf(cv.y, qv.y, acc);
            acc = fmaf(cv.z, qv.z, acc);
            acc = fmaf(cv.w, qv.w, acc);
        }
        acc += __shfl_xor(acc, 1);
        acc += __shfl_xor(acc, 2);
        acc += __shfl_xor(acc, 4);
        if (l == 0) scL[s] = acc;
    }
    __syncthreads();
    if (tid < 64) {  // softmax over 64 src positions
        float v = scL[tid];
        float m = v;
#pragma unroll
        for (int off = 32; off; off >>= 1) m = fmaxf(m, __shfl_xor(m, off));
        float e = __expf(v - m);
        float sum = e;
#pragma unroll
        for (int off = 32; off; off >>= 1) sum += __shfl_xor(sum, off);
        float p = e / sum;
        pl[tid] = p;
        outAtt[((size_t)tstep * 64 + b) * 64 + tid] = p;
    }
    __syncthreads();
    {   // cvec[h] = sum_s p[s]*ctx[s,b,h] -> LDS, then coalesced 8B publish
        float* cvL = qL;
        const float* cp = ctx + (size_t)b * 512 + tid;
        float acc = 0.f;
#pragma unroll 8
        for (int s = 0; s < 64; ++s)
            acc = fmaf(pl[s], cp[(size_t)s * 32768], acc);
        cvL[tid] = acc;
    }
    __syncthreads();
    if (tid < 256) {
        float* cvL = qL;
        pub2(&cvB[(size_t)b * 512 + 2 * tid], cvL[2 * tid], cvL[2 * tid + 1]);
    }
}

// ---------------- the whole decoder: one persistent kernel -------------------
__global__ __launch_bounds__(512, 1) void k_fused(
    const int* __restrict__ toks, const float* __restrict__ ctx,
    const float* __restrict__ emb,
    const float* __restrict__ Wih0, const float* __restrict__ Whh0,
    const float* __restrict__ bih0, const float* __restrict__ bhh0,
    const float* __restrict__ Wih1, const float* __restrict__ Whh1,
    const float* __restrict__ bih1, const float* __restrict__ bhh1,
    const float* __restrict__ Wa, const float* __restrict__ Wout,
    float* h0A, float* h1A, float* c0T, float* c1T,
    float* feedA, float* cvecA,
    float* outMain, float* outAtt, float* outHf, float* outCf, float* outFeedf,
    unsigned* barArr)
{
    __shared__ float WA[8 * 1536];     // 48 KB  LSTM0 rows [emb|feed|h0 : 1536]
    __shared__ float WB[8 * 1024];     // 32 KB  LSTM1 rows [h0n|h1 : 1024]
    __shared__ float WD[2 * 1024];     // 8 KB   Wout rows  [cvec|h1n : 1024]
    __shared__ float XT[128 * 68];     // 34.8 KB staging tile (attn scratch aliases)
    __shared__ float GW[8 * 16 * 36];  // 18.4 KB cross-wave K-reduce
    __shared__ float GS[8 * 68];       // 2.2 KB gate sums
    unsigned* flags = barArr;
    unsigned* rel   = barArr + NB * FSTR;
    const int bid = blockIdx.x, tid = threadIdx.x;

    const int kq   = tid >> 4;          // 0..31
    const int rAB  = (tid >> 1) & 7;    // row within block (A/B): gate*2+hh
    const int bvAB = tid & 1;
    const int rD   = (tid >> 3) & 1;
    const int bvD  = tid & 7;

    // -------- load this block's weight rows into LDS (once) --------
#pragma unroll
    for (int r = 0; r < 8; ++r) {
        int rowg = (r >> 1) * 512 + 2 * bid + (r & 1);
        if (tid < 384) {
            int k4 = tid * 4;
            float4 v = (k4 < 1024)
                ? *(const float4*)(Wih0 + (size_t)rowg * 1024 + k4)
                : *(const float4*)(Whh0 + (size_t)rowg * 512 + (k4 - 1024));
            *(float4*)&WA[r * 1536 + k4] = v;
        }
        if (tid < 256) {
            int k4 = tid * 4;
            float4 v = (k4 < 512)
                ? *(const float4*)(Wih1 + (size_t)rowg * 512 + k4)
                : *(const float4*)(Whh1 + (size_t)rowg * 512 + (k4 - 512));
            *(float4*)&WB[r * 1024 + k4] = v;
        }
    }
    {
        int r = tid >> 8, k4 = (tid & 255) * 4;
        *(float4*)&WD[r * 1024 + k4] =
            *(const float4*)(Wout + (size_t)(2 * bid + r) * 1024 + k4);
    }

    const float* wlA = WA + rAB * 1536 + kq * 4;
    const float* wlB = WB + rAB * 1024 + kq * 4;
    const float* wlD = WD + rD  * 1024 + kq * 4;

    // biases for the stage-1 reducer thread's (r,b)
    const int rFR = tid >> 6, gFR = rFR >> 1;
    const int hhFR = 2 * bid + (rFR & 1);
    const float biasA = bih0[gFR * 512 + hhFR] + bhh0[gFR * 512 + hhFR];
    const float biasB = bih1[gFR * 512 + hhFR] + bhh1[gFR * 512 + hhFR];

    float4 acc[8];
    unsigned g = 0;
    for (int t = 0; t < 32; ++t) {
        const float* h0c = h0A + (size_t)t * 32768;
        float*       h0n = h0A + (size_t)(t + 1) * 32768;
        const float* h1c = h1A + (size_t)t * 32768;
        float*       h1n = h1A + (size_t)(t + 1) * 32768;
        const float* fdc = feedA + (size_t)t * 32768;
        float*       fdn = feedA + (size_t)(t + 1) * 32768;
        float*       cvc = cvecA + (size_t)t * 32768;   // [b][512] this step
        const float* er  = emb + (size_t)toks[t * 64 + (tid >> 3)] * 512;

        // ---------- Phase A: LSTM0 gates (K=1536 = [emb|feed|h0old]) ----------
#pragma unroll
        for (int j = 0; j < 8; ++j) acc[j] = {0.f, 0.f, 0.f, 0.f};
        gemm_phase<12, 4, 8>(XT, wlA, acc, nullptr, fdc, h0c, er, tid, kq, bvAB * 32);
        waveRed(acc, 8);
        if (((tid >> 4) & 3) == 0) {
            float* gw = GW + ((tid >> 6) * 16 + (tid & 15)) * 36;
#pragma unroll
            for (int j = 0; j < 8; ++j) *(float4*)(gw + 4 * j) = acc[j];
        }
        __syncthreads();
        {   // stage-1: reduce 8 waves -> biased gate sums
            int r = tid >> 6, b = tid & 63;
            int grp = r * 2 + (b >> 5), idx = b & 31;
            float v = biasA;
#pragma unroll
            for (int w = 0; w < 8; ++w) v += GW[(w * 16 + grp) * 36 + idx];
            GS[r * 68 + b] = v;
        }
        __syncthreads();
        if (tid < 64) {   // LSTM0 cell, 2 b's per thread, 8B publish
            int hhl = tid >> 5, b0 = (tid & 31) * 2;
            int hh = 2 * bid + hhl;
            float gi0 = GS[(0 + hhl) * 68 + b0], gi1 = GS[(0 + hhl) * 68 + b0 + 1];
            float gf0 = GS[(2 + hhl) * 68 + b0], gf1 = GS[(2 + hhl) * 68 + b0 + 1];
            float gg0 = GS[(4 + hhl) * 68 + b0], gg1 = GS[(4 + hhl) * 68 + b0 + 1];
            float go0 = GS[(6 + hhl) * 68 + b0], go1 = GS[(6 + hhl) * 68 + b0 + 1];
            float2 c2 = *(float2*)&c0T[hh * 64 + b0];
            float cn0 = sigm(gf0) * c2.x + sigm(gi0) * tanh_(gg0);
            float cn1 = sigm(gf1) * c2.y + sigm(gi1) * tanh_(gg1);
            float hn0 = sigm(go0) * tanh_(cn0);
            float hn1 = sigm(go1) * tanh_(cn1);
            *(float2*)&c0T[hh * 64 + b0] = {cn0, cn1};
            pub2(&h0n[hh * 64 + b0], hn0, hn1);
            if (t == 31) {
                outHf[b0 * 512 + hh] = hn0; outHf[(b0 + 1) * 512 + hh] = hn1;
                outCf[b0 * 512 + hh] = cn0; outCf[(b0 + 1) * 512 + hh] = cn1;
            }
        }
        gbar(flags, rel, ++g);

        // ---------- Phase B: LSTM1 gates (K=1024 = [h0new|h1old]) ----------
#pragma unroll
        for (int j = 0; j < 8; ++j) acc[j] = {0.f, 0.f, 0.f, 0.f};
        gemm_phase<8, 0, 8>(XT, wlB, acc, h0n, h1c, nullptr, nullptr, tid, kq, bvAB * 32);
        waveRed(acc, 8);
        if (((tid >> 4) & 3) == 0) {
            float* gw = GW + ((tid >> 6) * 16 + (tid & 15)) * 36;
#pragma unroll
            for (int j = 0; j < 8; ++j) *(float4*)(gw + 4 * j) = acc[j];
        }
        __syncthreads();
        {
            int r = tid >> 6, b = tid & 63;
            int grp = r * 2 + (b >> 5), idx = b & 31;
            float v = biasB;
#pragma unroll
            for (int w = 0; w < 8; ++w) v += GW[(w * 16 + grp) * 36 + idx];
            GS[r * 68 + b] = v;
        }
        __syncthreads();
        if (tid < 64) {   // LSTM1 cell
            int hhl = tid >> 5, b0 = (tid & 31) * 2;
            int hh = 2 * bid + hhl;
            float gi0 = GS[(0 + hhl) * 68 + b0], gi1 = GS[(0 + hhl) * 68 + b0 + 1];
            float gf0 = GS[(2 + hhl) * 68 + b0], gf1 = GS[(2 + hhl) * 68 + b0 + 1];
            float gg0 = GS[(4 + hhl) * 68 + b0], gg1 = GS[(4 + hhl) * 68 + b0 + 1];
            float go0 = GS[(6 + hhl) * 68 + b0], go1 = GS[(6 + hhl) * 68 + b0 + 1];
            float2 c2 = *(float2*)&c1T[hh * 64 + b0];
            float cn0 = sigm(gf0) * c2.x + sigm(gi0) * tanh_(gg0);
            float cn1 = sigm(gf1) * c2.y + sigm(gi1) * tanh_(gg1);
            float hn0 = sigm(go0) * tanh_(cn0);
            float hn1 = sigm(go1) * tanh_(cn1);
            *(float2*)&c1T[hh * 64 + b0] = {cn0, cn1};
            pub2(&h1n[hh * 64 + b0], hn0, hn1);
            if (t == 31) {
                outHf[32768 + b0 * 512 + hh] = hn0; outHf[32768 + (b0 + 1) * 512 + hh] = hn1;
                outCf[32768 + b0 * 512 + hh] = cn0; outCf[32768 + (b0 + 1) * 512 + hh] = cn1;
            }
        }
        gbar(flags, rel, ++g);

        // ---------- Phase C: attention (blocks 0-63); others warm next emb ----
        if (bid < 64) {
            attn_block(XT, bid, tid, ctx, Wa, h1n, cvc, outAtt, t);
        } else if (t + 1 < 32) {
            // warm next step's embedding rows into LLC (covers HBM latency)
            const float* ern = emb + (size_t)toks[(t + 1) * 64 + (tid >> 3)] * 512;
            int seg = (bid >> 3) & 7;
            float4 a = *(const float4*)(ern + seg * 64 + (tid & 7) * 8);
            float4 b2 = *(const float4*)(ern + seg * 64 + (tid & 7) * 8 + 4);
            asm volatile("" :: "v"(a.x), "v"(b2.x));
        }
        gbar(flags, rel, ++g);

        // ---------- Phase D: out = tanh(Wout @ [cvec|h1new]) ----------
        acc[0] = {0.f, 0.f, 0.f, 0.f};
        acc[1] = {0.f, 0.f, 0.f, 0.f};
        {   // cvec half gathered from [b][512] rows (emb-style), h1n linear
            const float* cvRow = cvc + (size_t)(tid >> 3) * 512;
            gemm_phase<8, 4, 2>(XT, wlD, acc, nullptr, h1n, nullptr, cvRow,
                                tid, kq, bvD * 8);
        }
        waveRed(acc, 2);
        if (((tid >> 4) & 3) == 0) {
            float* gw = GW + ((tid >> 6) * 16 + (tid & 15)) * 36;
            *(float4*)(gw)     = acc[0];
            *(float4*)(gw + 4) = acc[1];
        }
        __syncthreads();
        if (tid < 64) {
            int rr = tid >> 5, b0 = (tid & 31) * 2;
            int grp = rr * 8 + (b0 >> 3), i0 = b0 & 7;
            float v0 = 0.f, v1 = 0.f;
#pragma unroll
            for (int w = 0; w < 8; ++w) {
                v0 += GW[(w * 16 + grp) * 36 + i0];
                v1 += GW[(w * 16 + grp) * 36 + i0 + 1];
            }
            float ah0 = tanh_(v0), ah1 = tanh_(v1);
            int o = 2 * bid + rr;
            outMain[((size_t)t * 64 + b0) * 512 + o] = ah0;
            outMain[((size_t)t * 64 + b0 + 1) * 512 + o] = ah1;
            pub2(&fdn[o * 64 + b0], ah0, ah1);
            if (t == 31) {
                outFeedf[b0 * 512 + o] = ah0;
                outFeedf[(b0 + 1) * 512 + o] = ah1;
            }
        }
        gbar(flags, rel, ++g);
    }
}

extern "C" void kernel_launch(void* const* d_in, const int* in_sizes, int n_in,
                              void* d_out, int out_size, void* d_ws, size_t ws_size,
                              hipStream_t stream) {
    const int*   toks  = (const int*)d_in[0];
    const float* ctx   = (const float*)d_in[2];
    const float* h0i   = (const float*)d_in[3];
    const float* c0i   = (const float*)d_in[4];
    const float* feedi = (const float*)d_in[5];
    const float* emb   = (const float*)d_in[6];
    const float* Wih0  = (const float*)d_in[7];
    const float* Whh0  = (const float*)d_in[8];
    const float* bih0  = (const float*)d_in[9];
    const float* bhh0  = (const float*)d_in[10];
    const float* Wih1  = (const float*)d_in[11];
    const float* Whh1  = (const float*)d_in[12];
    const float* bih1  = (const float*)d_in[13];
    const float* bhh1  = (const float*)d_in[14];
    const float* Wa    = (const float*)d_in[15];
    const float* Wout  = (const float*)d_in[16];

    // workspace: write-once arenas + block-private c-state + padded barrier
    float* ws    = (float*)d_ws;
    float* h0A   = ws;                    // 33 * 32768
    float* h1A   = h0A + 33 * 32768;      // 33 * 32768
    float* feedA = h1A + 33 * 32768;      // 33 * 32768
    float* cvecA = feedA + 33 * 32768;    // 32 * 32768 ([b][512] per slot)
    float* c0T   = cvecA + 32 * 32768;    // 32768
    float* c1T   = c0T + 32768;           // 32768
    unsigned* barArr = (unsigned*)(c1T + 32768);  // (256+32)*32 u32, line-padded

    float* out      = (float*)d_out;
    float* outMain  = out;             // [T,B,H]
    float* outAtt   = out + 1048576;   // [T,B,S]
    float* outHf    = out + 1179648;   // [L,B,H]
    float* outCf    = out + 1245184;   // [L,B,H]
    float* outFeedf = out + 1310720;   // [B,H]

    hipLaunchKernelGGL(k_init, dim3(128), dim3(256), 0, stream,
                       h0i, c0i, feedi, h0A, h1A, c0T, c1T, feedA, barArr);

    hipLaunchKernelGGL(k_fused, dim3(NB), dim3(512), 0, stream,
                       toks, ctx, emb, Wih0, Whh0, bih0, bhh0,
                       Wih1, Whh1, bih1, bhh1, Wa, Wout,
                       h0A, h1A, c0T, c1T, feedA, cvecA,
                       outMain, outAtt, outHf, outCf, outFeedf, barArr);
}

// Round 7
// 2105.676 us; speedup vs baseline: 2.2305x; 1.1720x over previous
//
#include <hip/hip_runtime.h>
#include <cstdint>

#define NB 256
#define FSTR 32   // u32 stride per barrier line (128 B) — one LLC line per word

__device__ __forceinline__ float sigm(float x) { return 1.f / (1.f + __expf(-x)); }
__device__ __forceinline__ float tanh_(float x) { return 1.f - 2.f / (1.f + __expf(2.f * x)); }

__device__ __forceinline__ void fma4(float4& a, float s, const float4& x) {
    a.x = fmaf(s, x.x, a.x); a.y = fmaf(s, x.y, a.y);
    a.z = fmaf(s, x.z, a.z); a.w = fmaf(s, x.w, a.w);
}

// publish two packed floats (8 B) to the LLC coherence point.
__device__ __forceinline__ void pub2(float* p, float a, float b) {
    unsigned long long u = ((unsigned long long)__float_as_uint(b) << 32) |
                           (unsigned long long)__float_as_uint(a);
    __hip_atomic_store((unsigned long long*)p, u, __ATOMIC_RELAXED,
                       __HIP_MEMORY_SCOPE_AGENT);
}

__device__ __forceinline__ unsigned ldf(const unsigned* p) {
    return __hip_atomic_load(p, __ATOMIC_RELAXED, __HIP_MEMORY_SCOPE_AGENT);
}
__device__ __forceinline__ void stf(unsigned* p, unsigned v) {
    __hip_atomic_store(p, v, __ATOMIC_RELAXED, __HIP_MEMORY_SCOPE_AGENT);
}

// ---------------- grid barrier: line-padded flags, replicated release, backoff
__device__ __forceinline__ void gbar(unsigned* flags, unsigned* rel, unsigned g) {
    asm volatile("s_waitcnt vmcnt(0)" ::: "memory");  // pub stores at LLC
    __syncthreads();
    const int tid = threadIdx.x, bid = blockIdx.x;
    if (bid == 0) {
        if (tid >= 1 && tid < NB) {
            const unsigned* f = flags + tid * FSTR;
            if (ldf(f) < g) { __builtin_amdgcn_s_sleep(4);
              if (ldf(f) < g) { __builtin_amdgcn_s_sleep(8);
                while (ldf(f) < g) __builtin_amdgcn_s_sleep(16); } }
        }
        __syncthreads();  // all arrivals observed
        if (tid < 32) stf(rel + tid * FSTR, g);
    } else if (tid == 0) {
        stf(flags + bid * FSTR, g);
        const unsigned* r = rel + (bid & 31) * FSTR;
        if (ldf(r) < g) { __builtin_amdgcn_s_sleep(4);
          if (ldf(r) < g) { __builtin_amdgcn_s_sleep(8);
            while (ldf(r) < g) __builtin_amdgcn_s_sleep(16); } }
    }
    __syncthreads();
}

// ---------------- init: states into transposed [h][b] slot-0 arenas ----------
__global__ __launch_bounds__(256) void k_init(const float* __restrict__ h0i,
                                              const float* __restrict__ c0i,
                                              const float* __restrict__ feedi,
                                              float* h0A, float* h1A, float* c0T, float* c1T,
                                              float* feedA, unsigned* barArr) {
    int t = blockIdx.x * 256 + threadIdx.x;  // 32768 = 512*64
    if (t < (NB + 32) * FSTR) barArr[t] = 0u;  // flags[256] + rel[32], line-padded
    int hh = t >> 6, b = t & 63;
    h0A[t]   = h0i[b * 512 + hh];
    h1A[t]   = h0i[32768 + b * 512 + hh];
    c0T[t]   = c0i[b * 512 + hh];
    c1T[t]   = c0i[32768 + b * 512 + hh];
    feedA[t] = feedi[b * 512 + hh];
}

// ---------------- LDS-weight GEMM phase (X-reuse decomposition) --------------
// Thread (bq = tid&15, kq = tid>>4) computes ALL `ROWS` rows for its 4-batch
// quad (b = 4bq..4bq+3) over its 4 k's (k = 4kq..4kq+3) per 128-k chunk.
// Per chunk: 4 X float4 reads (once, reused across rows from regs) + ROWS W
// float4 reads (16-lane broadcast, conflict-free) — was 33 reads/chunk.
// Staging (incl. XOR swizzle col = b ^ (k&12)) identical to the proven path;
// read col collapses to per-thread constant 4*(bq^(kq&3)).
// acc[r] holds the thread's 4-b partial per row; K-reduce done by caller.
template<int NCH, int GCH, int ROWS>
__device__ __forceinline__ void gemm_phase(
    float* XT, const float* wbase, int wstride, float4* acc,
    const float* s0T, const float* s1T, const float* s2T,
    const float* er, const int tid)
{
    const int bq = tid & 15;
    const int kq = tid >> 4;
    const int colX = 4 * (bq ^ (kq & 3));
    float4 st[4];
    const int q = tid & 7;
    // prefetch chunk 0
    if (GCH > 0) {
#pragma unroll
        for (int j = 0; j < 4; ++j)
            st[j] = *(const float4*)(er + (q + j * 8) * 4);
    } else {
#pragma unroll
        for (int j = 0; j < 4; ++j)
            st[j] = *(const float4*)(s0T + (size_t)(tid + j * 512) * 4);
    }
#pragma unroll
    for (int c = 0; c < NCH; ++c) {
        __syncthreads();   // previous XT consumers done
        if (GCH > 0 && c < GCH) {
            const int b = tid >> 3;
#pragma unroll
            for (int j = 0; j < 4; ++j) {
                int kl = (q + j * 8) * 4;
                int col = b ^ (kl & 12);   // (kl+i)&12 == kl&12 for i<4
                XT[(kl + 0) * 68 + col] = st[j].x;
                XT[(kl + 1) * 68 + col] = st[j].y;
                XT[(kl + 2) * 68 + col] = st[j].z;
                XT[(kl + 3) * 68 + col] = st[j].w;
            }
        } else {
#pragma unroll
            for (int j = 0; j < 4; ++j) {
                int f = tid + j * 512;
                int k = f >> 4, bq4 = (f & 15) * 4;
                *(float4*)&XT[k * 68 + (bq4 ^ (k & 12))] = st[j];
            }
        }
        __syncthreads();
        // prefetch next chunk (in flight during FMA)
        if (c + 1 < NCH) {
            if (GCH > 0 && (c + 1) < GCH) {
#pragma unroll
                for (int j = 0; j < 4; ++j)
                    st[j] = *(const float4*)(er + (c + 1) * 128 + (q + j * 8) * 4);
            } else {
                const int cc = c + 1;
                const int seg = cc >> 2;
                const float* sT = (seg == 0) ? s0T : (seg == 1) ? s1T : s2T;
#pragma unroll
                for (int j = 0; j < 4; ++j)
                    st[j] = *(const float4*)(sT + (size_t)((cc & 3) * 2048 + tid + j * 512) * 4);
            }
        }
        // weights for this chunk: ROWS float4 (broadcast across 16 bq lanes)
        float4 wv[ROWS];
#pragma unroll
        for (int r = 0; r < ROWS; ++r)
            wv[r] = *(const float4*)&wbase[r * wstride + c * 128 + kq * 4];
        // X once into regs, reused across all rows
        const float* xr = XT + (kq * 4) * 68 + colX;
        float4 x0 = *(const float4*)(xr);
        float4 x1 = *(const float4*)(xr + 68);
        float4 x2 = *(const float4*)(xr + 136);
        float4 x3 = *(const float4*)(xr + 204);
#pragma unroll
        for (int r = 0; r < ROWS; ++r) {
            fma4(acc[r], wv[r].x, x0);
            fma4(acc[r], wv[r].y, x1);
            fma4(acc[r], wv[r].z, x2);
            fma4(acc[r], wv[r].w, x3);
        }
    }
}

// in-wave K-reduce over the wave's 4 kq values (tid bits 4,5)
__device__ __forceinline__ void waveRed(float4* acc, int n) {
#pragma unroll
    for (int j = 0; j < 8; ++j) {
        if (j >= n) break;
        float4 v = acc[j];
        v.x += __shfl_xor(v.x, 16); v.y += __shfl_xor(v.y, 16);
        v.z += __shfl_xor(v.z, 16); v.w += __shfl_xor(v.w, 16);
        v.x += __shfl_xor(v.x, 32); v.y += __shfl_xor(v.y, 32);
        v.z += __shfl_xor(v.z, 32); v.w += __shfl_xor(v.w, 32);
        acc[j] = v;
    }
}

// ---------------- per-batch attention; cvec published coalesced [b][512] -----
__device__ __forceinline__ void attn_block(float* smem, int b, int tid,
                                           const float* __restrict__ ctx,
                                           const float* __restrict__ Wa,
                                           const float* __restrict__ h1n,
                                           float* __restrict__ cvB,
                                           float* __restrict__ outAtt, int tstep)
{
    float* hcol = smem;          // [512]
    float* qL   = smem + 512;    // [512]  (reused as cvL later)
    float* pl   = smem + 1024;   // [64]
    float* scL  = smem + 1088;   // [64]
    hcol[tid] = h1n[(size_t)tid * 64 + b];
    __syncthreads();
    {   // q[h] = dot(Wa[h,:], hcol)
        int l = tid & 7;
#pragma unroll
        for (int rep = 0; rep < 8; ++rep) {
            int h = rep * 64 + (tid >> 3);
            const float* wr = Wa + (size_t)h * 512 + l * 4;
            float acc = 0.f;
#pragma unroll
            for (int it = 0; it < 16; ++it) {
                float4 wv = *(const float4*)(wr + it * 32);
                float4 hv = *(const float4*)&hcol[l * 4 + it * 32];
                acc = fmaf(wv.x, hv.x, acc);
                acc = fmaf(wv.y, hv.y, acc);
                acc = fmaf(wv.z, hv.z, acc);
                acc = fmaf(wv.w, hv.w, acc);
            }
            acc += __shfl_xor(acc, 1);
            acc += __shfl_xor(acc, 2);
            acc += __shfl_xor(acc, 4);
            if (l == 0) qL[h] = acc;
        }
    }
    __syncthreads();
    {   // scores[s] = dot(q, ctx[s,b,:])
        int s = tid >> 3, l = tid & 7;
        const float* cr = ctx + ((size_t)s * 64 + b) * 512 + l * 4;
        float acc = 0.f;
#pragma unroll
        for (int it = 0; it < 16; ++it) {
            float4 cv = *(const float4*)(cr + it * 32);
            float4 qv = *(const float4*)&qL[l * 4 + it * 32];
            acc = fmaf(cv.x, qv.x, acc);
            acc = fmaf(cv.y, qv.y, acc);
            acc = fmaf(cv.z, qv.z, acc);
            acc = fmaf(cv.w, qv.w, acc);
        }
        acc += __shfl_xor(acc, 1);
        acc += __shfl_xor(acc, 2);
        acc += __shfl_xor(acc, 4);
        if (l == 0) scL[s] = acc;
    }
    __syncthreads();
    if (tid < 64) {  // softmax over 64 src positions
        float v = scL[tid];
        float m = v;
#pragma unroll
        for (int off = 32; off; off >>= 1) m = fmaxf(m, __shfl_xor(m, off));
        float e = __expf(v - m);
        float sum = e;
#pragma unroll
        for (int off = 32; off; off >>= 1) sum += __shfl_xor(sum, off);
        float p = e / sum;
        pl[tid] = p;
        outAtt[((size_t)tstep * 64 + b) * 64 + tid] = p;
    }
    __syncthreads();
    {   // cvec[h] = sum_s p[s]*ctx[s,b,h] -> LDS, then coalesced 8B publish
        float* cvL = qL;
        const float* cp = ctx + (size_t)b * 512 + tid;
        float acc = 0.f;
#pragma unroll 8
        for (int s = 0; s < 64; ++s)
            acc = fmaf(pl[s], cp[(size_t)s * 32768], acc);
        cvL[tid] = acc;
    }
    __syncthreads();
    if (tid < 256) {
        float* cvL = qL;
        pub2(&cvB[(size_t)b * 512 + 2 * tid], cvL[2 * tid], cvL[2 * tid + 1]);
    }
}

// ---------------- the whole decoder: one persistent kernel -------------------
__global__ __launch_bounds__(512, 1) void k_fused(
    const int* __restrict__ toks, const float* __restrict__ ctx,
    const float* __restrict__ emb,
    const float* __restrict__ Wih0, const float* __restrict__ Whh0,
    const float* __restrict__ bih0, const float* __restrict__ bhh0,
    const float* __restrict__ Wih1, const float* __restrict__ Whh1,
    const float* __restrict__ bih1, const float* __restrict__ bhh1,
    const float* __restrict__ Wa, const float* __restrict__ Wout,
    float* h0A, float* h1A, float* c0T, float* c1T,
    float* feedA, float* cvecA,
    float* outMain, float* outAtt, float* outHf, float* outCf, float* outFeedf,
    unsigned* barArr)
{
    __shared__ float WA[8 * 1536];     // 48 KB  LSTM0 rows [emb|feed|h0 : 1536]
    __shared__ float WB[8 * 1024];     // 32 KB  LSTM1 rows [h0n|h1 : 1024]
    __shared__ float WD[2 * 1024];     // 8 KB   Wout rows  [cvec|h1n : 1024]
    __shared__ float XT[128 * 68];     // 34.8 KB staging tile (attn scratch aliases)
    __shared__ float GW[8 * 16 * 36];  // 18 KB  cross-wave K-reduce [w][bq][r][4]
    __shared__ float GS[8 * 68];       // 2.2 KB gate sums
    unsigned* flags = barArr;
    unsigned* rel   = barArr + NB * FSTR;
    const int bid = blockIdx.x, tid = threadIdx.x;

    // -------- load this block's weight rows into LDS (once) --------
#pragma unroll
    for (int r = 0; r < 8; ++r) {
        int rowg = (r >> 1) * 512 + 2 * bid + (r & 1);
        if (tid < 384) {
            int k4 = tid * 4;
            float4 v = (k4 < 1024)
                ? *(const float4*)(Wih0 + (size_t)rowg * 1024 + k4)
                : *(const float4*)(Whh0 + (size_t)rowg * 512 + (k4 - 1024));
            *(float4*)&WA[r * 1536 + k4] = v;
        }
        if (tid < 256) {
            int k4 = tid * 4;
            float4 v = (k4 < 512)
                ? *(const float4*)(Wih1 + (size_t)rowg * 512 + k4)
                : *(const float4*)(Whh1 + (size_t)rowg * 512 + (k4 - 512));
            *(float4*)&WB[r * 1024 + k4] = v;
        }
    }
    {
        int r = tid >> 8, k4 = (tid & 255) * 4;
        *(float4*)&WD[r * 1024 + k4] =
            *(const float4*)(Wout + (size_t)(2 * bid + r) * 1024 + k4);
    }

    // biases for the stage-1 reducer thread's (r,b)
    const int rFR = tid >> 6, gFR = rFR >> 1;
    const int hhFR = 2 * bid + (rFR & 1);
    const float biasA = bih0[gFR * 512 + hhFR] + bhh0[gFR * 512 + hhFR];
    const float biasB = bih1[gFR * 512 + hhFR] + bhh1[gFR * 512 + hhFR];

    float4 acc[8];
    unsigned g = 0;
    for (int t = 0; t < 32; ++t) {
        const float* h0c = h0A + (size_t)t * 32768;
        float*       h0n = h0A + (size_t)(t + 1) * 32768;
        const float* h1c = h1A + (size_t)t * 32768;
        float*       h1n = h1A + (size_t)(t + 1) * 32768;
        const float* fdc = feedA + (size_t)t * 32768;
        float*       fdn = feedA + (size_t)(t + 1) * 32768;
        float*       cvc = cvecA + (size_t)t * 32768;   // [b][512] this step
        const float* er  = emb + (size_t)toks[t * 64 + (tid >> 3)] * 512;

        // ---------- Phase A: LSTM0 gates (K=1536 = [emb|feed|h0old]) ----------
#pragma unroll
        for (int j = 0; j < 8; ++j) acc[j] = {0.f, 0.f, 0.f, 0.f};
        gemm_phase<12, 4, 8>(XT, WA, 1536, acc, nullptr, fdc, h0c, er, tid);
        waveRed(acc, 8);
        if ((tid & 48) == 0) {
            float* gw = GW + ((tid >> 6) * 16 + (tid & 15)) * 36;
#pragma unroll
            for (int r = 0; r < 8; ++r) *(float4*)(gw + 4 * r) = acc[r];
        }
        __syncthreads();
        {   // stage-1: reduce 8 waves -> biased gate sums
            int r = tid >> 6, b = tid & 63;
            const float* gwp = GW + (b >> 2) * 36 + r * 4 + (b & 3);
            float v = biasA;
#pragma unroll
            for (int w = 0; w < 8; ++w) v += gwp[w * 576];
            GS[r * 68 + b] = v;
        }
        __syncthreads();
        if (tid < 64) {   // LSTM0 cell, 2 b's per thread, 8B publish
            int hhl = tid >> 5, b0 = (tid & 31) * 2;
            int hh = 2 * bid + hhl;
            float gi0 = GS[(0 + hhl) * 68 + b0], gi1 = GS[(0 + hhl) * 68 + b0 + 1];
            float gf0 = GS[(2 + hhl) * 68 + b0], gf1 = GS[(2 + hhl) * 68 + b0 + 1];
            float gg0 = GS[(4 + hhl) * 68 + b0], gg1 = GS[(4 + hhl) * 68 + b0 + 1];
            float go0 = GS[(6 + hhl) * 68 + b0], go1 = GS[(6 + hhl) * 68 + b0 + 1];
            float2 c2 = *(float2*)&c0T[hh * 64 + b0];
            float cn0 = sigm(gf0) * c2.x + sigm(gi0) * tanh_(gg0);
            float cn1 = sigm(gf1) * c2.y + sigm(gi1) * tanh_(gg1);
            float hn0 = sigm(go0) * tanh_(cn0);
            float hn1 = sigm(go1) * tanh_(cn1);
            *(float2*)&c0T[hh * 64 + b0] = {cn0, cn1};
            pub2(&h0n[hh * 64 + b0], hn0, hn1);
            if (t == 31) {
                outHf[b0 * 512 + hh] = hn0; outHf[(b0 + 1) * 512 + hh] = hn1;
                outCf[b0 * 512 + hh] = cn0; outCf[(b0 + 1) * 512 + hh] = cn1;
            }
        }
        gbar(flags, rel, ++g);

        // ---------- Phase B: LSTM1 gates (K=1024 = [h0new|h1old]) ----------
#pragma unroll
        for (int j = 0; j < 8; ++j) acc[j] = {0.f, 0.f, 0.f, 0.f};
        gemm_phase<8, 0, 8>(XT, WB, 1024, acc, h0n, h1c, nullptr, nullptr, tid);
        waveRed(acc, 8);
        if ((tid & 48) == 0) {
            float* gw = GW + ((tid >> 6) * 16 + (tid & 15)) * 36;
#pragma unroll
            for (int r = 0; r < 8; ++r) *(float4*)(gw + 4 * r) = acc[r];
        }
        __syncthreads();
        {
            int r = tid >> 6, b = tid & 63;
            const float* gwp = GW + (b >> 2) * 36 + r * 4 + (b & 3);
            float v = biasB;
#pragma unroll
            for (int w = 0; w < 8; ++w) v += gwp[w * 576];
            GS[r * 68 + b] = v;
        }
        __syncthreads();
        if (tid < 64) {   // LSTM1 cell
            int hhl = tid >> 5, b0 = (tid & 31) * 2;
            int hh = 2 * bid + hhl;
            float gi0 = GS[(0 + hhl) * 68 + b0], gi1 = GS[(0 + hhl) * 68 + b0 + 1];
            float gf0 = GS[(2 + hhl) * 68 + b0], gf1 = GS[(2 + hhl) * 68 + b0 + 1];
            float gg0 = GS[(4 + hhl) * 68 + b0], gg1 = GS[(4 + hhl) * 68 + b0 + 1];
            float go0 = GS[(6 + hhl) * 68 + b0], go1 = GS[(6 + hhl) * 68 + b0 + 1];
            float2 c2 = *(float2*)&c1T[hh * 64 + b0];
            float cn0 = sigm(gf0) * c2.x + sigm(gi0) * tanh_(gg0);
            float cn1 = sigm(gf1) * c2.y + sigm(gi1) * tanh_(gg1);
            float hn0 = sigm(go0) * tanh_(cn0);
            float hn1 = sigm(go1) * tanh_(cn1);
            *(float2*)&c1T[hh * 64 + b0] = {cn0, cn1};
            pub2(&h1n[hh * 64 + b0], hn0, hn1);
            if (t == 31) {
                outHf[32768 + b0 * 512 + hh] = hn0; outHf[32768 + (b0 + 1) * 512 + hh] = hn1;
                outCf[32768 + b0 * 512 + hh] = cn0; outCf[32768 + (b0 + 1) * 512 + hh] = cn1;
            }
        }
        gbar(flags, rel, ++g);

        // ---------- Phase C: attention (blocks 0-63); others warm next emb ----
        if (bid < 64) {
            attn_block(XT, bid, tid, ctx, Wa, h1n, cvc, outAtt, t);
        } else if (t + 1 < 32) {
            // warm next step's embedding rows into LLC (covers HBM latency)
            const float* ern = emb + (size_t)toks[(t + 1) * 64 + (tid >> 3)] * 512;
            int seg = (bid >> 3) & 7;
            float4 a = *(const float4*)(ern + seg * 64 + (tid & 7) * 8);
            float4 b2 = *(const float4*)(ern + seg * 64 + (tid & 7) * 8 + 4);
            asm volatile("" :: "v"(a.x), "v"(b2.x));
        }
        gbar(flags, rel, ++g);

        // ---------- Phase D: out = tanh(Wout @ [cvec|h1new]) ----------
        acc[0] = {0.f, 0.f, 0.f, 0.f};
        acc[1] = {0.f, 0.f, 0.f, 0.f};
        {   // cvec half gathered from [b][512] rows (emb-style), h1n linear
            const float* cvRow = cvc + (size_t)(tid >> 3) * 512;
            gemm_phase<8, 4, 2>(XT, WD, 1024, acc, nullptr, h1n, nullptr, cvRow, tid);
        }
        waveRed(acc, 2);
        if ((tid & 48) == 0) {
            float* gw = GW + ((tid >> 6) * 16 + (tid & 15)) * 36;
            *(float4*)(gw)     = acc[0];
            *(float4*)(gw + 4) = acc[1];
        }
        __syncthreads();
        if (tid < 64) {
            int rr = tid >> 5, b0 = (tid & 31) * 2;
            const float* g0 = GW + (b0 >> 2) * 36 + rr * 4 + (b0 & 3);
            float v0 = 0.f, v1 = 0.f;
#pragma unroll
            for (int w = 0; w < 8; ++w) { v0 += g0[w * 576]; v1 += g0[w * 576 + 1]; }
            float ah0 = tanh_(v0), ah1 = tanh_(v1);
            int o = 2 * bid + rr;
            outMain[((size_t)t * 64 + b0) * 512 + o] = ah0;
            outMain[((size_t)t * 64 + b0 + 1) * 512 + o] = ah1;
            pub2(&fdn[o * 64 + b0], ah0, ah1);
            if (t == 31) {
                outFeedf[b0 * 512 + o] = ah0;
                outFeedf[(b0 + 1) * 512 + o] = ah1;
            }
        }
        gbar(flags, rel, ++g);
    }
}

extern "C" void kernel_launch(void* const* d_in, const int* in_sizes, int n_in,
                              void* d_out, int out_size, void* d_ws, size_t ws_size,
                              hipStream_t stream) {
    const int*   toks  = (const int*)d_in[0];
    const float* ctx   = (const float*)d_in[2];
    const float* h0i   = (const float*)d_in[3];
    const float* c0i   = (const float*)d_in[4];
    const float* feedi = (const float*)d_in[5];
    const float* emb   = (const float*)d_in[6];
    const float* Wih0  = (const float*)d_in[7];
    const float* Whh0  = (const float*)d_in[8];
    const float* bih0  = (const float*)d_in[9];
    const float* bhh0  = (const float*)d_in[10];
    const float* Wih1  = (const float*)d_in[11];
    const float* Whh1  = (const float*)d_in[12];
    const float* bih1  = (const float*)d_in[13];
    const float* bhh1  = (const float*)d_in[14];
    const float* Wa    = (const float*)d_in[15];
    const float* Wout  = (const float*)d_in[16];

    // workspace: write-once arenas + block-private c-state + padded barrier
    float* ws    = (float*)d_ws;
    float* h0A   = ws;                    // 33 * 32768
    float* h1A   = h0A + 33 * 32768;      // 33 * 32768
    float* feedA = h1A + 33 * 32768;      // 33 * 32768
    float* cvecA = feedA + 33 * 32768;    // 32 * 32768 ([b][512] per slot)
    float* c0T   = cvecA + 32 * 32768;    // 32768
    float* c1T   = c0T + 32768;           // 32768
    unsigned* barArr = (unsigned*)(c1T + 32768);  // (256+32)*32 u32, line-padded

    float* out      = (float*)d_out;
    float* outMain  = out;             // [T,B,H]
    float* outAtt   = out + 1048576;   // [T,B,S]
    float* outHf    = out + 1179648;   // [L,B,H]
    float* outCf    = out + 1245184;   // [L,B,H]
    float* outFeedf = out + 1310720;   // [B,H]

    hipLaunchKernelGGL(k_init, dim3(128), dim3(256), 0, stream,
                       h0i, c0i, feedi, h0A, h1A, c0T, c1T, feedA, barArr);

    hipLaunchKernelGGL(k_fused, dim3(NB), dim3(512), 0, stream,
                       toks, ctx, emb, Wih0, Whh0, bih0, bhh0,
                       Wih1, Whh1, bih1, bhh1, Wa, Wout,
                       h0A, h1A, c0T, c1T, feedA, cvecA,
                       outMain, outAtt, outHf, outCf, outFeedf, barArr);
}